// Round 10
// baseline (38.465 us; speedup 1.0000x reference)
//
#include <hip/hip_runtime.h>
#include <hip/hip_bf16.h>
#if !__has_builtin(__builtin_amdgcn_cvt_pk_fp8_f32)
#include <hip/hip_fp8.h>
#endif

// NT-Xent loss, MI355X. B=4096, D=256, N=8192, temp=0.5.
// R10 = R9 (fp8 e4m3 MX MFMA, scale=1.0) re-dimensioned for occupancy:
// per-wave work 64x512 -> 64x256 (JSPLIT 32, grid 1024 blocks = 4096 waves)
// and __launch_bounds__(256,3) -> 3 blocks/CU (3 waves/SIMD, cap 170 VGPR;
// fp8 A-frags are only 64 regs, live set ~155 fits). R4-R9 showed the MFMA/
// LDS/TRANS poles run nearly serially at 2 waves/SIMD lockstep; +50% TLP
// overlaps them. Everything else (reuse-4, swizzled staging, deferred
// epilogue, reg-dbuf ds_reads) unchanged from R9.

typedef __attribute__((ext_vector_type(4))) float f32x4;
typedef __attribute__((ext_vector_type(8))) int i32x8;

#define N_TOT 8192
#define B_HALF 4096
#define D_DIM 256
#define JSPLIT 32
#define JCOLS 256
#define NSTEP 4
#define SCL_PRE 1.6986436f             // sqrt((1/T)*log2 e) = sqrt(2.8853901)
#define RES_SCALE 0.6931471805599453f  // ln2: sim = acc * ln2 after prescale
#define SONE 0x7F7F7F7F                // E8M0 scale bytes = 127 -> 2^0 = 1.0

__device__ inline float fexp2(float x) {
#if __has_builtin(__builtin_amdgcn_exp2f)
  return __builtin_amdgcn_exp2f(x);  // raw v_exp_f32; args in [-2.9, 2.9]
#else
  return exp2f(x);
#endif
}

__device__ inline unsigned pack_fp8x4(float x, float y, float z, float w) {
#if __has_builtin(__builtin_amdgcn_cvt_pk_fp8_f32)
  int r = 0;
  r = __builtin_amdgcn_cvt_pk_fp8_f32(x, y, r, false);  // bytes 0,1
  r = __builtin_amdgcn_cvt_pk_fp8_f32(z, w, r, true);   // bytes 2,3
  return (unsigned)r;
#else
  __hip_fp8_e4m3 a(x), b(y), c(z), d(w);
  return (unsigned)a.__x | ((unsigned)b.__x << 8) | ((unsigned)c.__x << 16) |
         ((unsigned)d.__x << 24);
#endif
}

__device__ inline i32x8 ld32(const char* p0, const char* p1) {
  int4 lo = *reinterpret_cast<const int4*>(p0);
  int4 hi = *reinterpret_cast<const int4*>(p1);
  i32x8 r = {lo.x, lo.y, lo.z, lo.w, hi.x, hi.y, hi.z, hi.w};
  return r;
}

__global__ __launch_bounds__(256) void nrm_kernel(const float* __restrict__ z1,
                                                  const float* __restrict__ z2,
                                                  unsigned* __restrict__ zn8) {
  int row = blockIdx.x * 4 + (threadIdx.x >> 6);
  int lane = threadIdx.x & 63;
  const float* src = (row < B_HALF) ? (z1 + (size_t)row * D_DIM)
                                    : (z2 + (size_t)(row - B_HALF) * D_DIM);
  f32x4 v = *reinterpret_cast<const f32x4*>(src + lane * 4);
  float ss = v.x * v.x + v.y * v.y + v.z * v.z + v.w * v.w;
#pragma unroll
  for (int m = 32; m >= 1; m >>= 1) ss += __shfl_xor(ss, m);
  float inv = SCL_PRE / fmaxf(sqrtf(ss), 1e-8f);  // normalize + exp2 prescale
  zn8[(size_t)row * 64 + lane] =
      pack_fp8x4(v.x * inv, v.y * inv, v.z * inv, v.w * inv);
}

__global__ __launch_bounds__(256, 3) void gram_kernel(const unsigned* __restrict__ zn8,
                                                      float* __restrict__ psum,
                                                      float* __restrict__ ppos) {
  __shared__ __align__(16) char bt[2 * 64 * 256];  // double-buffered fp8 B panels
  const int tid = threadIdx.x;
  const int w = tid >> 6, l = tid & 63;
  const int lm = l & 15, hh = l >> 4;
  const int r0w = blockIdx.x * 256 + w * 64;  // this wave's 64 i-rows
  const int jbase = blockIdx.y * JCOLS;
  const char* znb = reinterpret_cast<const char*>(zn8);

  // stage step s (64 B-rows x 256B fp8) into buffer bi. LDS dest linear
  // (uniform base + lane*16); swizzle realized by XOR on the global source.
  auto stage = [&](int s, int bi) {
    const char* gs = znb + (size_t)(jbase + s * 64) * 256;
    char* base = bt + bi * 16384 + w * 1024;
#pragma unroll
    for (int q = 0; q < 4; ++q) {
      int rloc = q * 16 + w * 4 + (l >> 4);
      const char* g = gs + (size_t)rloc * 256 + (((l & 15) * 16) ^ ((rloc & 7) << 4));
      __builtin_amdgcn_global_load_lds(
          (const __attribute__((address_space(1))) void*)g,
          (__attribute__((address_space(3))) void*)(base + q * 4096), 16, 0, 0);
    }
  };

  stage(0, 0);  // prefetch first panel; overlaps the A-fragment loads below

  // A fragments: 64 rows x K=256 fp8 in registers. lane: row lm (+rf*16),
  // k-bytes sl*128 + hh*32 .. +31. B mirrors this (Gram symmetry).
  i32x8 a[4][2];
#pragma unroll
  for (int rf = 0; rf < 4; ++rf)
#pragma unroll
    for (int sl = 0; sl < 2; ++sl) {
      const char* ab = znb + (size_t)(r0w + rf * 16 + lm) * 256 + sl * 128 + hh * 32;
      a[rf][sl] = ld32(ab, ab + 16);
    }

  float sume[4][4];
#pragma unroll
  for (int rf = 0; rf < 4; ++rf)
#pragma unroll
    for (int t = 0; t < 4; ++t) sume[rf][t] = 0.f;

  const int swz = (lm & 7) << 4;  // row = jt*16+lm -> row&7 == lm&7

  i32x8 bh0, bh1;         // register-double-buffered B slices (K=128 each)
  f32x4 acA[4], acB[4];   // ping-pong accumulators (static indexing)
  int pjtb = -1;

  // read one B slice: 16 cols x K=128 = 32B/lane, two swizzled ds_read_b128
  auto readS = [&](const char* bp, int jt, int sl, i32x8& b) {
    const char* row = bp + (jt * 16 + lm) * 256;
    int cs = (sl * 128 + hh * 32) ^ swz;
    b = ld32(row + cs, row + (cs ^ 16));
  };

  // epilogue of a finished tile: exp + LSE partial + diag mask + positive
  auto epilogue = [&](const f32x4 (&pa)[4], int jtb) {
#pragma unroll
    for (int rf = 0; rf < 4; ++rf) {
      const int itb = r0w + rf * 16;
      const bool dg = (itb == jtb);
      const bool ps = ((itb ^ B_HALF) == jtb);
      if (dg | ps) {  // wave-uniform; at most 8 of 64 tiles per wave
#pragma unroll
        for (int t = 0; t < 4; ++t) {
          float sv = pa[rf][t];
          float e = fexp2(sv);
          bool self = (lm == hh * 4 + t);  // C/D map: row=hh*4+t, col=lm
          if (dg && self) e = 0.f;         // mask diagonal
          sume[rf][t] += e;
          if (ps && self) ppos[itb + hh * 4 + t] = sv * RES_SCALE;
        }
      } else {
#pragma unroll
        for (int t = 0; t < 4; ++t) sume[rf][t] += fexp2(pa[rf][t]);
      }
    }
  };

  auto mfma4 = [&](f32x4 (&acc)[4], const i32x8& b, int sl) {
    __builtin_amdgcn_s_setprio(1);
#pragma unroll
    for (int rf = 0; rf < 4; ++rf)
      acc[rf] = __builtin_amdgcn_mfma_scale_f32_16x16x128_f8f6f4(
          a[rf][sl], b, acc[rf], 0, 0, 0, SONE, 0, SONE);
    __builtin_amdgcn_s_setprio(0);
  };

  for (int s = 0; s < NSTEP; ++s) {
    __syncthreads();  // drains my stage loads + all waves done w/ prev buf
    if (s + 1 < NSTEP) stage(s + 1, (s + 1) & 1);  // async prefetch under compute
    const char* bp = bt + (s & 1) * 16384;

    readS(bp, 0, 0, bh0);  // prologue: first slice of this step
#pragma unroll
    for (int jt = 0; jt < 4; ++jt) {
      f32x4(&acc)[4] = (jt & 1) ? acB : acA;
      f32x4(&prev)[4] = (jt & 1) ? acA : acB;

      readS(bp, jt, 1, bh1);                // in flight during epilogue+MFMA
      if (pjtb >= 0) epilogue(prev, pjtb);  // VALU under read latency
#pragma unroll
      for (int rf = 0; rf < 4; ++rf) acc[rf] = (f32x4){0.f, 0.f, 0.f, 0.f};
      mfma4(acc, bh0, 0);
      if (jt < 3) readS(bp, jt + 1, 0, bh0);  // in flight during MFMA(bh1)
      mfma4(acc, bh1, 1);
      pjtb = jbase + s * 64 + jt * 16;
    }
  }
  epilogue(acB, pjtb);  // last tile was jt=3 -> acB

  // reduce partial sums across the 16 lanes (lm) sharing each row
#pragma unroll
  for (int rf = 0; rf < 4; ++rf)
#pragma unroll
    for (int t = 0; t < 4; ++t) {
      float v = sume[rf][t];
#pragma unroll
      for (int m = 1; m < 16; m <<= 1) v += __shfl_xor(v, m);
      if (lm == 0) psum[(size_t)blockIdx.y * N_TOT + r0w + rf * 16 + hh * 4 + t] = v;
    }
}

__global__ __launch_bounds__(256) void fin1_kernel(const float* __restrict__ psum,
                                                   const float* __restrict__ ppos,
                                                   float* __restrict__ partial) {
  int i = blockIdx.x * 256 + threadIdx.x;
  float se = 0.f;
#pragma unroll
  for (int s = 0; s < JSPLIT; ++s) se += psum[(size_t)s * N_TOT + i];
  float acc = logf(se) - ppos[i];
#pragma unroll
  for (int m = 32; m >= 1; m >>= 1) acc += __shfl_xor(acc, m);
  __shared__ float red[4];
  if ((threadIdx.x & 63) == 0) red[threadIdx.x >> 6] = acc;
  __syncthreads();
  if (threadIdx.x == 0) partial[blockIdx.x] = red[0] + red[1] + red[2] + red[3];
}

__global__ void fin2_kernel(const float* __restrict__ partial, float* __restrict__ out) {
  float v = (threadIdx.x < 32) ? partial[threadIdx.x] : 0.f;
#pragma unroll
  for (int m = 32; m >= 1; m >>= 1) v += __shfl_xor(v, m);
  if (threadIdx.x == 0) out[0] = v / (float)N_TOT;
}

extern "C" void kernel_launch(void* const* d_in, const int* in_sizes, int n_in,
                              void* d_out, int out_size, void* d_ws, size_t ws_size,
                              hipStream_t stream) {
  const float* z1 = (const float*)d_in[0];
  const float* z2 = (const float*)d_in[1];
  float* out = (float*)d_out;
  char* ws = (char*)d_ws;

  unsigned* zn8 = (unsigned*)ws;                            // 2 MiB fp8
  float* psum = (float*)(ws + (size_t)N_TOT * D_DIM);       // 32*8192 f32 = 1 MiB
  float* ppos = psum + (size_t)JSPLIT * N_TOT;              // 8192 f32
  float* partial = ppos + N_TOT;                            // 32 f32

  nrm_kernel<<<N_TOT / 4, 256, 0, stream>>>(z1, z2, zn8);
  gram_kernel<<<dim3(N_TOT / 256, JSPLIT), 256, 0, stream>>>(zn8, psum, ppos);
  fin1_kernel<<<N_TOT / 256, 256, 0, stream>>>(psum, ppos, partial);
  fin2_kernel<<<1, 64, 0, stream>>>(partial, out);
}

// Round 11
// 37.791 us; speedup vs baseline: 1.0178x; 1.0178x over previous
//
#include <hip/hip_runtime.h>
#include <hip/hip_bf16.h>
#if !__has_builtin(__builtin_amdgcn_cvt_pk_fp8_f32)
#include <hip/hip_fp8.h>
#endif

// NT-Xent loss, MI355X. B=4096, D=256, N=8192, temp=0.5.
// R11 = R9 (fp8 e4m3 MX MFMA, JSPLIT=16, (…,2) reg tier) with the block
// shrunk 256->128 threads (2 waves): same 2 waves/SIMD, but 4 INDEPENDENT
// blocks/CU (vs 2) whose barrier domains are 2 waves (vs 4). R4-R10 showed
// serial-sum pipe behavior from lockstep phases; independent blocks drift
// into anti-phase so MFMA/exp/LDS overlap across blocks. Grid 64x16 = 1024
// = exactly 4 blocks/CU * 256 CU, zero tail. R10 lesson: (256,3)'s 170-reg
// cap + 33% tail regressed; this keeps the 256-reg tier.

typedef __attribute__((ext_vector_type(4))) float f32x4;
typedef __attribute__((ext_vector_type(8))) int i32x8;

#define N_TOT 8192
#define B_HALF 4096
#define D_DIM 256
#define JSPLIT 16
#define JCOLS 512
#define NSTEP 8
#define SCL_PRE 1.6986436f             // sqrt((1/T)*log2 e) = sqrt(2.8853901)
#define RES_SCALE 0.6931471805599453f  // ln2: sim = acc * ln2 after prescale
#define SONE 0x7F7F7F7F                // E8M0 scale bytes = 127 -> 2^0 = 1.0

__device__ inline float fexp2(float x) {
#if __has_builtin(__builtin_amdgcn_exp2f)
  return __builtin_amdgcn_exp2f(x);  // raw v_exp_f32; args in [-2.9, 2.9]
#else
  return exp2f(x);
#endif
}

__device__ inline unsigned pack_fp8x4(float x, float y, float z, float w) {
#if __has_builtin(__builtin_amdgcn_cvt_pk_fp8_f32)
  int r = 0;
  r = __builtin_amdgcn_cvt_pk_fp8_f32(x, y, r, false);  // bytes 0,1
  r = __builtin_amdgcn_cvt_pk_fp8_f32(z, w, r, true);   // bytes 2,3
  return (unsigned)r;
#else
  __hip_fp8_e4m3 a(x), b(y), c(z), d(w);
  return (unsigned)a.__x | ((unsigned)b.__x << 8) | ((unsigned)c.__x << 16) |
         ((unsigned)d.__x << 24);
#endif
}

__device__ inline i32x8 ld32(const char* p0, const char* p1) {
  int4 lo = *reinterpret_cast<const int4*>(p0);
  int4 hi = *reinterpret_cast<const int4*>(p1);
  i32x8 r = {lo.x, lo.y, lo.z, lo.w, hi.x, hi.y, hi.z, hi.w};
  return r;
}

__global__ __launch_bounds__(256) void nrm_kernel(const float* __restrict__ z1,
                                                  const float* __restrict__ z2,
                                                  unsigned* __restrict__ zn8) {
  int row = blockIdx.x * 4 + (threadIdx.x >> 6);
  int lane = threadIdx.x & 63;
  const float* src = (row < B_HALF) ? (z1 + (size_t)row * D_DIM)
                                    : (z2 + (size_t)(row - B_HALF) * D_DIM);
  f32x4 v = *reinterpret_cast<const f32x4*>(src + lane * 4);
  float ss = v.x * v.x + v.y * v.y + v.z * v.z + v.w * v.w;
#pragma unroll
  for (int m = 32; m >= 1; m >>= 1) ss += __shfl_xor(ss, m);
  float inv = SCL_PRE / fmaxf(sqrtf(ss), 1e-8f);  // normalize + exp2 prescale
  zn8[(size_t)row * 64 + lane] =
      pack_fp8x4(v.x * inv, v.y * inv, v.z * inv, v.w * inv);
}

__global__ __launch_bounds__(128, 2) void gram_kernel(const unsigned* __restrict__ zn8,
                                                      float* __restrict__ psum,
                                                      float* __restrict__ ppos) {
  __shared__ __align__(16) char bt[2 * 64 * 256];  // double-buffered fp8 B panels
  const int tid = threadIdx.x;
  const int w = tid >> 6, l = tid & 63;  // 2 waves/block
  const int lm = l & 15, hh = l >> 4;
  const int r0w = blockIdx.x * 128 + w * 64;  // this wave's 64 i-rows
  const int jbase = blockIdx.y * JCOLS;
  const char* znb = reinterpret_cast<const char*>(zn8);

  // stage step s (64 B-rows x 256B fp8) into buffer bi. LDS dest linear
  // (uniform base + lane*16); swizzle realized by XOR on the global source.
  // 128 threads x 8 quanta x 16B = 16KB panel; q covers rows q*8..q*8+7.
  auto stage = [&](int s, int bi) {
    const char* gs = znb + (size_t)(jbase + s * 64) * 256;
    char* base = bt + bi * 16384 + w * 1024;
#pragma unroll
    for (int q = 0; q < 8; ++q) {
      int rloc = q * 8 + w * 4 + (l >> 4);
      const char* g = gs + (size_t)rloc * 256 + (((l & 15) * 16) ^ ((rloc & 7) << 4));
      __builtin_amdgcn_global_load_lds(
          (const __attribute__((address_space(1))) void*)g,
          (__attribute__((address_space(3))) void*)(base + q * 2048), 16, 0, 0);
    }
  };

  stage(0, 0);  // prefetch first panel; overlaps the A-fragment loads below

  // A fragments: 64 rows x K=256 fp8 in registers. lane: row lm (+rf*16),
  // k-bytes sl*128 + hh*32 .. +31. B mirrors this (Gram symmetry).
  i32x8 a[4][2];
#pragma unroll
  for (int rf = 0; rf < 4; ++rf)
#pragma unroll
    for (int sl = 0; sl < 2; ++sl) {
      const char* ab = znb + (size_t)(r0w + rf * 16 + lm) * 256 + sl * 128 + hh * 32;
      a[rf][sl] = ld32(ab, ab + 16);
    }

  float sume[4][4];
#pragma unroll
  for (int rf = 0; rf < 4; ++rf)
#pragma unroll
    for (int t = 0; t < 4; ++t) sume[rf][t] = 0.f;

  const int swz = (lm & 7) << 4;  // row = jt*16+lm -> row&7 == lm&7

  i32x8 bh0, bh1;         // register-double-buffered B slices (K=128 each)
  f32x4 acA[4], acB[4];   // ping-pong accumulators (static indexing)
  int pjtb = -1;

  // read one B slice: 16 cols x K=128 = 32B/lane, two swizzled ds_read_b128
  auto readS = [&](const char* bp, int jt, int sl, i32x8& b) {
    const char* row = bp + (jt * 16 + lm) * 256;
    int cs = (sl * 128 + hh * 32) ^ swz;
    b = ld32(row + cs, row + (cs ^ 16));
  };

  // epilogue of a finished tile: exp + LSE partial + diag mask + positive
  auto epilogue = [&](const f32x4 (&pa)[4], int jtb) {
#pragma unroll
    for (int rf = 0; rf < 4; ++rf) {
      const int itb = r0w + rf * 16;
      const bool dg = (itb == jtb);
      const bool ps = ((itb ^ B_HALF) == jtb);
      if (dg | ps) {  // wave-uniform; rare special tiles
#pragma unroll
        for (int t = 0; t < 4; ++t) {
          float sv = pa[rf][t];
          float e = fexp2(sv);
          bool self = (lm == hh * 4 + t);  // C/D map: row=hh*4+t, col=lm
          if (dg && self) e = 0.f;         // mask diagonal
          sume[rf][t] += e;
          if (ps && self) ppos[itb + hh * 4 + t] = sv * RES_SCALE;
        }
      } else {
#pragma unroll
        for (int t = 0; t < 4; ++t) sume[rf][t] += fexp2(pa[rf][t]);
      }
    }
  };

  auto mfma4 = [&](f32x4 (&acc)[4], const i32x8& b, int sl) {
    __builtin_amdgcn_s_setprio(1);
#pragma unroll
    for (int rf = 0; rf < 4; ++rf)
      acc[rf] = __builtin_amdgcn_mfma_scale_f32_16x16x128_f8f6f4(
          a[rf][sl], b, acc[rf], 0, 0, 0, SONE, 0, SONE);
    __builtin_amdgcn_s_setprio(0);
  };

  for (int s = 0; s < NSTEP; ++s) {
    __syncthreads();  // drains my stage loads + both waves done w/ prev buf
    if (s + 1 < NSTEP) stage(s + 1, (s + 1) & 1);  // async prefetch under compute
    const char* bp = bt + (s & 1) * 16384;

    readS(bp, 0, 0, bh0);  // prologue: first slice of this step
#pragma unroll
    for (int jt = 0; jt < 4; ++jt) {
      f32x4(&acc)[4] = (jt & 1) ? acB : acA;
      f32x4(&prev)[4] = (jt & 1) ? acA : acB;

      readS(bp, jt, 1, bh1);                // in flight during epilogue+MFMA
      if (pjtb >= 0) epilogue(prev, pjtb);  // VALU under read latency
#pragma unroll
      for (int rf = 0; rf < 4; ++rf) acc[rf] = (f32x4){0.f, 0.f, 0.f, 0.f};
      mfma4(acc, bh0, 0);
      if (jt < 3) readS(bp, jt + 1, 0, bh0);  // in flight during MFMA(bh1)
      mfma4(acc, bh1, 1);
      pjtb = jbase + s * 64 + jt * 16;
    }
  }
  epilogue(acB, pjtb);  // last tile was jt=3 -> acB

  // reduce partial sums across the 16 lanes (lm) sharing each row
#pragma unroll
  for (int rf = 0; rf < 4; ++rf)
#pragma unroll
    for (int t = 0; t < 4; ++t) {
      float v = sume[rf][t];
#pragma unroll
      for (int m = 1; m < 16; m <<= 1) v += __shfl_xor(v, m);
      if (lm == 0) psum[(size_t)blockIdx.y * N_TOT + r0w + rf * 16 + hh * 4 + t] = v;
    }
}

__global__ __launch_bounds__(256) void fin1_kernel(const float* __restrict__ psum,
                                                   const float* __restrict__ ppos,
                                                   float* __restrict__ partial) {
  int i = blockIdx.x * 256 + threadIdx.x;
  float se = 0.f;
#pragma unroll
  for (int s = 0; s < JSPLIT; ++s) se += psum[(size_t)s * N_TOT + i];
  float acc = logf(se) - ppos[i];
#pragma unroll
  for (int m = 32; m >= 1; m >>= 1) acc += __shfl_xor(acc, m);
  __shared__ float red[4];
  if ((threadIdx.x & 63) == 0) red[threadIdx.x >> 6] = acc;
  __syncthreads();
  if (threadIdx.x == 0) partial[blockIdx.x] = red[0] + red[1] + red[2] + red[3];
}

__global__ void fin2_kernel(const float* __restrict__ partial, float* __restrict__ out) {
  float v = (threadIdx.x < 32) ? partial[threadIdx.x] : 0.f;
#pragma unroll
  for (int m = 32; m >= 1; m >>= 1) v += __shfl_xor(v, m);
  if (threadIdx.x == 0) out[0] = v / (float)N_TOT;
}

extern "C" void kernel_launch(void* const* d_in, const int* in_sizes, int n_in,
                              void* d_out, int out_size, void* d_ws, size_t ws_size,
                              hipStream_t stream) {
  const float* z1 = (const float*)d_in[0];
  const float* z2 = (const float*)d_in[1];
  float* out = (float*)d_out;
  char* ws = (char*)d_ws;

  unsigned* zn8 = (unsigned*)ws;                            // 2 MiB fp8
  float* psum = (float*)(ws + (size_t)N_TOT * D_DIM);       // 16*8192 f32
  float* ppos = psum + (size_t)JSPLIT * N_TOT;              // 8192 f32
  float* partial = ppos + N_TOT;                            // 32 f32

  nrm_kernel<<<N_TOT / 4, 256, 0, stream>>>(z1, z2, zn8);
  gram_kernel<<<dim3(N_TOT / 128, JSPLIT), 128, 0, stream>>>(zn8, psum, ppos);
  fin1_kernel<<<N_TOT / 256, 256, 0, stream>>>(psum, ppos, partial);
  fin2_kernel<<<1, 64, 0, stream>>>(partial, out);
}

// Round 12
// 30.997 us; speedup vs baseline: 1.2409x; 1.2192x over previous
//
#include <hip/hip_runtime.h>
#include <hip/hip_bf16.h>

// NT-Xent loss, MI355X. B=4096, D=256, N=8192, temp=0.5.
// R12 = R9 skeleton with MX-fp4 (e2m1) instead of fp8: pole-shrink round.
// R4-R11 lesson: scheduling moves are <=5%; pole shrinks pay (R4 +21%, R9
// +27%). fp4 @16x16x128 = 7228 TF (m25) vs fp8 4661 -> MFMA pole 7.4->4.75us;
// LDS panel 16->8KB, one ds_read_b128 per slice; staging traffic halves.
// MX scaling: elements are ~N(0,0.106) after unit-norm+prescale -> raw e2m1
// grid would zero them. Encode x*16 (fills +-6 grid, 4-sigma clip) and set
// both E8M0 scale bytes to 123 (2^-4): 16*16*2^-4*2^-4 = 1 exactly.
// Gram symmetry shields pack-order/k-permutations (same loader for A and B);
// C/D map is shape-determined (row=(l>>4)*4+t, col=l&15).

typedef __attribute__((ext_vector_type(4))) float f32x4;
typedef __attribute__((ext_vector_type(8))) int i32x8;

#define N_TOT 8192
#define B_HALF 4096
#define D_DIM 256
#define JSPLIT 16
#define JCOLS 512
#define NSTEP 8
#define SCL_PRE 1.6986436f             // sqrt((1/T)*log2 e) = sqrt(2.8853901)
#define RES_SCALE 0.6931471805599453f  // ln2: sim = acc * ln2 after prescale
#define S4 0x7B7B7B7B                  // E8M0 123 -> 2^-4 per operand

__device__ inline float fexp2(float x) {
#if __has_builtin(__builtin_amdgcn_exp2f)
  return __builtin_amdgcn_exp2f(x);  // raw v_exp_f32; args in [-3.2, 3.2]
#else
  return exp2f(x);
#endif
}

// e2m1 encode, RNE against grid {0,.5,1,1.5,2,3,4,6}, clamp at 6
__device__ inline unsigned enc4(float v) {
  float av = fabsf(v);
  unsigned c = (av >= 0.25f) + (av >= 0.75f) + (av >= 1.25f) + (av >= 1.75f) +
               (av >= 2.5f) + (av >= 3.5f) + (av >= 5.0f);
  return c | ((v < 0.f) ? 8u : 0u);
}

__device__ inline i32x8 ld16z(const char* p) {
  int4 lo = *reinterpret_cast<const int4*>(p);
  i32x8 r = {lo.x, lo.y, lo.z, lo.w, 0, 0, 0, 0};  // fp4 uses low 4 regs
  return r;
}

__global__ __launch_bounds__(256) void nrm_kernel(const float* __restrict__ z1,
                                                  const float* __restrict__ z2,
                                                  unsigned short* __restrict__ zn4) {
  int row = blockIdx.x * 4 + (threadIdx.x >> 6);
  int lane = threadIdx.x & 63;
  const float* src = (row < B_HALF) ? (z1 + (size_t)row * D_DIM)
                                    : (z2 + (size_t)(row - B_HALF) * D_DIM);
  f32x4 v = *reinterpret_cast<const f32x4*>(src + lane * 4);
  float ss = v.x * v.x + v.y * v.y + v.z * v.z + v.w * v.w;
#pragma unroll
  for (int m = 32; m >= 1; m >>= 1) ss += __shfl_xor(ss, m);
  // normalize + exp2 prescale + fp4 grid fill (x16, compensated by S4 scales)
  float inv = (SCL_PRE * 16.0f) / fmaxf(sqrtf(ss), 1e-8f);
  unsigned n0 = enc4(v.x * inv), n1 = enc4(v.y * inv);
  unsigned n2 = enc4(v.z * inv), n3 = enc4(v.w * inv);
  // byte b holds elems 2b (low nibble), 2b+1 (high); lane covers elems 4L..4L+3
  zn4[(size_t)row * 64 + lane] =
      (unsigned short)(n0 | (n1 << 4) | (n2 << 8) | (n3 << 12));
}

__global__ __launch_bounds__(256, 2) void gram_kernel(const unsigned short* __restrict__ zn4,
                                                      float* __restrict__ psum,
                                                      float* __restrict__ ppos) {
  __shared__ __align__(16) char bt[2 * 64 * 128];  // double-buffered fp4 B panels
  const int tid = threadIdx.x;
  const int w = tid >> 6, l = tid & 63;
  const int lm = l & 15, hh = l >> 4;
  const int r0w = blockIdx.x * 256 + w * 64;  // this wave's 64 i-rows
  const int jbase = blockIdx.y * JCOLS;
  const char* znb = reinterpret_cast<const char*>(zn4);

  // stage step s (64 B-rows x 128B fp4) into buffer bi. LDS dest linear
  // (uniform base + lane*16); swizzle via XOR on the global source unit.
  auto stage = [&](int s, int bi) {
    const char* gs = znb + (size_t)(jbase + s * 64) * 128;
    char* base = bt + bi * 8192 + w * 1024;
#pragma unroll
    for (int q = 0; q < 2; ++q) {
      int rloc = q * 32 + w * 8 + (l >> 3);
      int d = l & 7;  // dest 16B unit within the row
      const char* g = gs + (size_t)rloc * 128 + ((d ^ (rloc & 7)) << 4);
      __builtin_amdgcn_global_load_lds(
          (const __attribute__((address_space(1))) void*)g,
          (__attribute__((address_space(3))) void*)(base + q * 4096), 16, 0, 0);
    }
  };

  stage(0, 0);  // prefetch first panel; overlaps the A-fragment loads below

  // A fragments: 64 rows x K=256 fp4 in registers. lane: row lm (+rf*16),
  // k-bytes sl*64 + hh*16 .. +15. B mirrors this (Gram symmetry).
  i32x8 a[4][2];
#pragma unroll
  for (int rf = 0; rf < 4; ++rf)
#pragma unroll
    for (int sl = 0; sl < 2; ++sl)
      a[rf][sl] = ld16z(znb + (size_t)(r0w + rf * 16 + lm) * 128 + sl * 64 + hh * 16);

  float sume[4][4];
#pragma unroll
  for (int rf = 0; rf < 4; ++rf)
#pragma unroll
    for (int t = 0; t < 4; ++t) sume[rf][t] = 0.f;

  const int swz = (lm & 7) << 4;  // row = jt*16+lm -> row&7 == lm&7

  i32x8 bh0, bh1;        // register-double-buffered B slices (K=128 each)
  f32x4 acA[4], acB[4];  // ping-pong accumulators (static indexing)
  int pjtb = -1;

  // read one B slice: 16 cols x K=128 = 16B/lane, one swizzled ds_read_b128
  auto readS = [&](const char* bp, int jt, int sl, i32x8& b) {
    const char* row = bp + (jt * 16 + lm) * 128;
    int cs = (sl * 64 + hh * 16) ^ swz;
    b = ld16z(row + cs);
  };

  // epilogue of a finished tile: exp + LSE partial + diag mask + positive
  auto epilogue = [&](const f32x4 (&pa)[4], int jtb) {
#pragma unroll
    for (int rf = 0; rf < 4; ++rf) {
      const int itb = r0w + rf * 16;
      const bool dg = (itb == jtb);
      const bool ps = ((itb ^ B_HALF) == jtb);
      if (dg | ps) {  // wave-uniform; rare special tiles
#pragma unroll
        for (int t = 0; t < 4; ++t) {
          float sv = pa[rf][t];
          float e = fexp2(sv);
          bool self = (lm == hh * 4 + t);  // C/D map: row=hh*4+t, col=lm
          if (dg && self) e = 0.f;         // mask diagonal
          sume[rf][t] += e;
          if (ps && self) ppos[itb + hh * 4 + t] = sv * RES_SCALE;
        }
      } else {
#pragma unroll
        for (int t = 0; t < 4; ++t) sume[rf][t] += fexp2(pa[rf][t]);
      }
    }
  };

  auto mfma4 = [&](f32x4 (&acc)[4], const i32x8& b, int sl) {
    __builtin_amdgcn_s_setprio(1);
#pragma unroll
    for (int rf = 0; rf < 4; ++rf)
      acc[rf] = __builtin_amdgcn_mfma_scale_f32_16x16x128_f8f6f4(
          a[rf][sl], b, acc[rf], 4, 4, 0, S4, 0, S4);  // fmt 4 = FP4
    __builtin_amdgcn_s_setprio(0);
  };

  for (int s = 0; s < NSTEP; ++s) {
    __syncthreads();  // drains my stage loads + all waves done w/ prev buf
    if (s + 1 < NSTEP) stage(s + 1, (s + 1) & 1);  // async prefetch under compute
    const char* bp = bt + (s & 1) * 8192;

    readS(bp, 0, 0, bh0);  // prologue: first slice of this step
#pragma unroll
    for (int jt = 0; jt < 4; ++jt) {
      f32x4(&acc)[4] = (jt & 1) ? acB : acA;
      f32x4(&prev)[4] = (jt & 1) ? acA : acB;

      readS(bp, jt, 1, bh1);                // in flight during epilogue+MFMA
      if (pjtb >= 0) epilogue(prev, pjtb);  // VALU under read latency
#pragma unroll
      for (int rf = 0; rf < 4; ++rf) acc[rf] = (f32x4){0.f, 0.f, 0.f, 0.f};
      mfma4(acc, bh0, 0);
      if (jt < 3) readS(bp, jt + 1, 0, bh0);  // in flight during MFMA(bh1)
      mfma4(acc, bh1, 1);
      pjtb = jbase + s * 64 + jt * 16;
    }
  }
  epilogue(acB, pjtb);  // last tile was jt=3 -> acB

  // reduce partial sums across the 16 lanes (lm) sharing each row
#pragma unroll
  for (int rf = 0; rf < 4; ++rf)
#pragma unroll
    for (int t = 0; t < 4; ++t) {
      float v = sume[rf][t];
#pragma unroll
      for (int m = 1; m < 16; m <<= 1) v += __shfl_xor(v, m);
      if (lm == 0) psum[(size_t)blockIdx.y * N_TOT + r0w + rf * 16 + hh * 4 + t] = v;
    }
}

__global__ __launch_bounds__(256) void fin1_kernel(const float* __restrict__ psum,
                                                   const float* __restrict__ ppos,
                                                   float* __restrict__ partial) {
  int i = blockIdx.x * 256 + threadIdx.x;
  float se = 0.f;
#pragma unroll
  for (int s = 0; s < JSPLIT; ++s) se += psum[(size_t)s * N_TOT + i];
  float acc = logf(se) - ppos[i];
#pragma unroll
  for (int m = 32; m >= 1; m >>= 1) acc += __shfl_xor(acc, m);
  __shared__ float red[4];
  if ((threadIdx.x & 63) == 0) red[threadIdx.x >> 6] = acc;
  __syncthreads();
  if (threadIdx.x == 0) partial[blockIdx.x] = red[0] + red[1] + red[2] + red[3];
}

__global__ void fin2_kernel(const float* __restrict__ partial, float* __restrict__ out) {
  float v = (threadIdx.x < 32) ? partial[threadIdx.x] : 0.f;
#pragma unroll
  for (int m = 32; m >= 1; m >>= 1) v += __shfl_xor(v, m);
  if (threadIdx.x == 0) out[0] = v / (float)N_TOT;
}

extern "C" void kernel_launch(void* const* d_in, const int* in_sizes, int n_in,
                              void* d_out, int out_size, void* d_ws, size_t ws_size,
                              hipStream_t stream) {
  const float* z1 = (const float*)d_in[0];
  const float* z2 = (const float*)d_in[1];
  float* out = (float*)d_out;
  char* ws = (char*)d_ws;

  unsigned short* zn4 = (unsigned short*)ws;            // 8192*128B = 1 MiB fp4
  float* psum = (float*)(ws + (size_t)N_TOT * 128);     // 16*8192 f32
  float* ppos = psum + (size_t)JSPLIT * N_TOT;          // 8192 f32
  float* partial = ppos + N_TOT;                        // 32 f32

  nrm_kernel<<<N_TOT / 4, 256, 0, stream>>>(z1, z2, zn4);
  gram_kernel<<<dim3(N_TOT / 256, JSPLIT), 256, 0, stream>>>(zn4, psum, ppos);
  fin1_kernel<<<N_TOT / 256, 256, 0, stream>>>(psum, ppos, partial);
  fin2_kernel<<<1, 64, 0, stream>>>(partial, out);
}

// Round 13
// 29.824 us; speedup vs baseline: 1.2897x; 1.0393x over previous
//
#include <hip/hip_runtime.h>
#include <hip/hip_bf16.h>

// NT-Xent loss, MI355X. B=4096, D=256, N=8192, temp=0.5.
// R13 = R12 (MX-fp4 e2m1, scale 2^-4 pair, x16 encode) re-dimensioned for
// 4 waves/SIMD: 32-row waves (a[2][2] fp4 frags = 16 live regs + shared
// zeros), 128-row x 512-col blocks, __launch_bounds__(256,4) (128-reg tier),
// grid 64x16 = 1024 = exactly 4 blocks/CU x 256 CU, ZERO tail.
// Rationale: R4-R12 scoreboard -> pole shrinks pay (R4 +21%, R9 +27%,
// R12 +15%), scheduling at 2 waves/SIMD <=5%. Remaining time is exposure
// from too little TLP; exp floor (67M v_exp @ 1/4 rate = 3.4us) + MFMA
// (4.5us) need 4+ waves/SIMD to overlap. R10's failed TLP attempt had fp8
// frags vs a 170 cap + 33% tail; fp4 + zero tail removes both confounds.

typedef __attribute__((ext_vector_type(4))) float f32x4;
typedef __attribute__((ext_vector_type(8))) int i32x8;

#define N_TOT 8192
#define B_HALF 4096
#define D_DIM 256
#define JSPLIT 16
#define JCOLS 512
#define NSTEP 8
#define SCL_PRE 1.6986436f             // sqrt((1/T)*log2 e) = sqrt(2.8853901)
#define RES_SCALE 0.6931471805599453f  // ln2: sim = acc * ln2 after prescale
#define S4 0x7B7B7B7B                  // E8M0 123 -> 2^-4 per operand

__device__ inline float fexp2(float x) {
#if __has_builtin(__builtin_amdgcn_exp2f)
  return __builtin_amdgcn_exp2f(x);  // raw v_exp_f32; args in [-3.2, 3.2]
#else
  return exp2f(x);
#endif
}

// e2m1 encode, RNE against grid {0,.5,1,1.5,2,3,4,6}, clamp at 6
__device__ inline unsigned enc4(float v) {
  float av = fabsf(v);
  unsigned c = (av >= 0.25f) + (av >= 0.75f) + (av >= 1.25f) + (av >= 1.75f) +
               (av >= 2.5f) + (av >= 3.5f) + (av >= 5.0f);
  return c | ((v < 0.f) ? 8u : 0u);
}

__device__ inline i32x8 ld16z(const char* p) {
  int4 lo = *reinterpret_cast<const int4*>(p);
  i32x8 r = {lo.x, lo.y, lo.z, lo.w, 0, 0, 0, 0};  // fp4 uses low 4 regs
  return r;
}

__global__ __launch_bounds__(256) void nrm_kernel(const float* __restrict__ z1,
                                                  const float* __restrict__ z2,
                                                  unsigned short* __restrict__ zn4) {
  int row = blockIdx.x * 4 + (threadIdx.x >> 6);
  int lane = threadIdx.x & 63;
  const float* src = (row < B_HALF) ? (z1 + (size_t)row * D_DIM)
                                    : (z2 + (size_t)(row - B_HALF) * D_DIM);
  f32x4 v = *reinterpret_cast<const f32x4*>(src + lane * 4);
  float ss = v.x * v.x + v.y * v.y + v.z * v.z + v.w * v.w;
#pragma unroll
  for (int m = 32; m >= 1; m >>= 1) ss += __shfl_xor(ss, m);
  // normalize + exp2 prescale + fp4 grid fill (x16, compensated by S4 scales)
  float inv = (SCL_PRE * 16.0f) / fmaxf(sqrtf(ss), 1e-8f);
  unsigned n0 = enc4(v.x * inv), n1 = enc4(v.y * inv);
  unsigned n2 = enc4(v.z * inv), n3 = enc4(v.w * inv);
  zn4[(size_t)row * 64 + lane] =
      (unsigned short)(n0 | (n1 << 4) | (n2 << 8) | (n3 << 12));
}

__global__ __launch_bounds__(256, 4) void gram_kernel(const unsigned short* __restrict__ zn4,
                                                      float* __restrict__ psum,
                                                      float* __restrict__ ppos) {
  __shared__ __align__(16) char bt[2 * 64 * 128];  // double-buffered fp4 B panels
  const int tid = threadIdx.x;
  const int w = tid >> 6, l = tid & 63;
  const int lm = l & 15, hh = l >> 4;
  const int r0w = blockIdx.x * 128 + w * 32;  // this wave's 32 i-rows
  const int jbase = blockIdx.y * JCOLS;
  const char* znb = reinterpret_cast<const char*>(zn4);

  // stage step s (64 B-rows x 128B fp4) into buffer bi. LDS dest linear
  // (uniform base + lane*16); swizzle via XOR on the global source unit.
  auto stage = [&](int s, int bi) {
    const char* gs = znb + (size_t)(jbase + s * 64) * 128;
    char* base = bt + bi * 8192 + w * 1024;
#pragma unroll
    for (int q = 0; q < 2; ++q) {
      int rloc = q * 32 + w * 8 + (l >> 3);
      int d = l & 7;  // dest 16B unit within the row
      const char* g = gs + (size_t)rloc * 128 + ((d ^ (rloc & 7)) << 4);
      __builtin_amdgcn_global_load_lds(
          (const __attribute__((address_space(1))) void*)g,
          (__attribute__((address_space(3))) void*)(base + q * 4096), 16, 0, 0);
    }
  };

  stage(0, 0);  // prefetch first panel; overlaps the A-fragment loads below

  // A fragments: 32 rows x K=256 fp4 in registers. lane: row lm (+rf*16),
  // k-bytes sl*64 + hh*16 .. +15. B mirrors this (Gram symmetry).
  i32x8 a[2][2];
#pragma unroll
  for (int rf = 0; rf < 2; ++rf)
#pragma unroll
    for (int sl = 0; sl < 2; ++sl)
      a[rf][sl] = ld16z(znb + (size_t)(r0w + rf * 16 + lm) * 128 + sl * 64 + hh * 16);

  float sume[2][4];
#pragma unroll
  for (int rf = 0; rf < 2; ++rf)
#pragma unroll
    for (int t = 0; t < 4; ++t) sume[rf][t] = 0.f;

  const int swz = (lm & 7) << 4;  // row = jt*16+lm -> row&7 == lm&7

  i32x8 bh0, bh1;        // register-double-buffered B slices (K=128 each)
  f32x4 acA[2], acB[2];  // ping-pong accumulators (static indexing)
  int pjtb = -1;

  // read one B slice: 16 cols x K=128 = 16B/lane, one swizzled ds_read_b128
  auto readS = [&](const char* bp, int jt, int sl, i32x8& b) {
    const char* row = bp + (jt * 16 + lm) * 128;
    int cs = (sl * 64 + hh * 16) ^ swz;
    b = ld16z(row + cs);
  };

  // epilogue of a finished tile: exp + LSE partial + diag mask + positive
  auto epilogue = [&](const f32x4 (&pa)[2], int jtb) {
#pragma unroll
    for (int rf = 0; rf < 2; ++rf) {
      const int itb = r0w + rf * 16;
      const bool dg = (itb == jtb);
      const bool ps = ((itb ^ B_HALF) == jtb);
      if (dg | ps) {  // wave-uniform; rare special tiles
#pragma unroll
        for (int t = 0; t < 4; ++t) {
          float sv = pa[rf][t];
          float e = fexp2(sv);
          bool self = (lm == hh * 4 + t);  // C/D map: row=hh*4+t, col=lm
          if (dg && self) e = 0.f;         // mask diagonal
          sume[rf][t] += e;
          if (ps && self) ppos[itb + hh * 4 + t] = sv * RES_SCALE;
        }
      } else {
#pragma unroll
        for (int t = 0; t < 4; ++t) sume[rf][t] += fexp2(pa[rf][t]);
      }
    }
  };

  auto mfma2 = [&](f32x4 (&acc)[2], const i32x8& b, int sl) {
    __builtin_amdgcn_s_setprio(1);
#pragma unroll
    for (int rf = 0; rf < 2; ++rf)
      acc[rf] = __builtin_amdgcn_mfma_scale_f32_16x16x128_f8f6f4(
          a[rf][sl], b, acc[rf], 4, 4, 0, S4, 0, S4);  // fmt 4 = FP4
    __builtin_amdgcn_s_setprio(0);
  };

  for (int s = 0; s < NSTEP; ++s) {
    __syncthreads();  // drains my stage loads + all waves done w/ prev buf
    if (s + 1 < NSTEP) stage(s + 1, (s + 1) & 1);  // async prefetch under compute
    const char* bp = bt + (s & 1) * 8192;

    readS(bp, 0, 0, bh0);  // prologue: first slice of this step
#pragma unroll
    for (int jt = 0; jt < 4; ++jt) {
      f32x4(&acc)[2] = (jt & 1) ? acB : acA;
      f32x4(&prev)[2] = (jt & 1) ? acA : acB;

      readS(bp, jt, 1, bh1);                // in flight during epilogue+MFMA
      if (pjtb >= 0) epilogue(prev, pjtb);  // VALU/trans under read latency
#pragma unroll
      for (int rf = 0; rf < 2; ++rf) acc[rf] = (f32x4){0.f, 0.f, 0.f, 0.f};
      mfma2(acc, bh0, 0);
      if (jt < 3) readS(bp, jt + 1, 0, bh0);  // in flight during MFMA(bh1)
      mfma2(acc, bh1, 1);
      pjtb = jbase + s * 64 + jt * 16;
    }
  }
  epilogue(acB, pjtb);  // last tile was jt=3 -> acB

  // reduce partial sums across the 16 lanes (lm) sharing each row
#pragma unroll
  for (int rf = 0; rf < 2; ++rf)
#pragma unroll
    for (int t = 0; t < 4; ++t) {
      float v = sume[rf][t];
#pragma unroll
      for (int m = 1; m < 16; m <<= 1) v += __shfl_xor(v, m);
      if (lm == 0) psum[(size_t)blockIdx.y * N_TOT + r0w + rf * 16 + hh * 4 + t] = v;
    }
}

__global__ __launch_bounds__(256) void fin1_kernel(const float* __restrict__ psum,
                                                   const float* __restrict__ ppos,
                                                   float* __restrict__ partial) {
  int i = blockIdx.x * 256 + threadIdx.x;
  float se = 0.f;
#pragma unroll
  for (int s = 0; s < JSPLIT; ++s) se += psum[(size_t)s * N_TOT + i];
  float acc = logf(se) - ppos[i];
#pragma unroll
  for (int m = 32; m >= 1; m >>= 1) acc += __shfl_xor(acc, m);
  __shared__ float red[4];
  if ((threadIdx.x & 63) == 0) red[threadIdx.x >> 6] = acc;
  __syncthreads();
  if (threadIdx.x == 0) partial[blockIdx.x] = red[0] + red[1] + red[2] + red[3];
}

__global__ void fin2_kernel(const float* __restrict__ partial, float* __restrict__ out) {
  float v = (threadIdx.x < 32) ? partial[threadIdx.x] : 0.f;
#pragma unroll
  for (int m = 32; m >= 1; m >>= 1) v += __shfl_xor(v, m);
  if (threadIdx.x == 0) out[0] = v / (float)N_TOT;
}

extern "C" void kernel_launch(void* const* d_in, const int* in_sizes, int n_in,
                              void* d_out, int out_size, void* d_ws, size_t ws_size,
                              hipStream_t stream) {
  const float* z1 = (const float*)d_in[0];
  const float* z2 = (const float*)d_in[1];
  float* out = (float*)d_out;
  char* ws = (char*)d_ws;

  unsigned short* zn4 = (unsigned short*)ws;            // 8192*128B = 1 MiB fp4
  float* psum = (float*)(ws + (size_t)N_TOT * 128);     // 16*8192 f32
  float* ppos = psum + (size_t)JSPLIT * N_TOT;          // 8192 f32
  float* partial = ppos + N_TOT;                        // 32 f32

  nrm_kernel<<<N_TOT / 4, 256, 0, stream>>>(z1, z2, zn4);
  gram_kernel<<<dim3(N_TOT / 128, JSPLIT), 256, 0, stream>>>(zn4, psum, ppos);
  fin1_kernel<<<N_TOT / 256, 256, 0, stream>>>(psum, ppos, partial);
  fin2_kernel<<<1, 64, 0, stream>>>(partial, out);
}